// Round 21
// baseline (51.195 us; speedup 1.0000x reference)
//
#include <hip/hip_runtime.h>
#include <math.h>
#include <stdint.h>

#define NN 8192
#define DD 1024
#define KT 2048   // 2*D
#define HH 100
#define LCAP 512
#define NB 32

typedef short bf16x8 __attribute__((ext_vector_type(8)));
typedef short bf16x4 __attribute__((ext_vector_type(4)));
typedef float f32x4 __attribute__((ext_vector_type(4)));

__device__ __forceinline__ short f2bf(float f) {
    uint32_t u = __builtin_bit_cast(uint32_t, f);
    u += 0x7FFF + ((u >> 16) & 1);   // RTNE
    return (short)(u >> 16);
}

// W1 fp32 [2048][100] -> w1p packed fragments (verified R9-R18).
// w1p[(c32*8 + tile)*512 + l*8 + j] = bf16(W1[c32*32 + (l>>4)*8 + j][tile*16 + (l&15)])
__global__ __launch_bounds__(256) void prep_w1p(const float* __restrict__ W1,
                                                short* __restrict__ w1p,
                                                int* __restrict__ cnt1,
                                                int* __restrict__ cnt0)
{
    __shared__ float ld[32][104];
    const int t  = threadIdx.x;
    if (blockIdx.x == 0 && t < 64) {
        if (t < 32) cnt1[t] = 0; else cnt0[t - 32] = 0;
    }
    const int k0 = blockIdx.x * 32;          // 64 blocks
    for (int i = t; i < 32 * HH; i += 256) {
        const int kk = i / HH, cc = i - kk * HH;
        ld[kk][cc] = W1[(size_t)(k0 + kk) * HH + cc];
    }
    __syncthreads();
    for (int idx = t; idx < 512; idx += 256) {
        const int tt = idx >> 6, l = idx & 63;
        const int lr = l & 15, lg = l >> 4;
        const int col = tt * 16 + lr;
        bf16x8 r;
#pragma unroll
        for (int j = 0; j < 8; ++j)
            r[j] = (col < HH) ? f2bf(ld[lg * 8 + j][col]) : (short)0;
        *(bf16x8*)(w1p + ((size_t)(blockIdx.x * 8 + tt) * 64 + l) * 8) = r;
    }
}

// M=32 rows/block, 256 blocks, 512 thr / 8 waves; 64 KB LDS -> 2 blocks/CU.
// Wave w owns col tile w (16 cols) x FULL K (B read once/block, disjoint/wave).
// A staged per K-half (q then x) into As[32][16][64] bf16, swizzled; 3 barriers.
__global__ __launch_bounds__(512) void encoder_mfma(
    const float* __restrict__ q, const float* __restrict__ x,
    const short* __restrict__ w1p,
    const float* __restrict__ b1, const float* __restrict__ W2,
    const float* __restrict__ b2,
    const int* __restrict__ bidx, const int* __restrict__ y,
    float* __restrict__ sp, float* __restrict__ sn,
    int* __restrict__ cnt1, int* __restrict__ cnt0)
{
    __shared__ short As[32][16][64];   // 64 KB: [row][chunk64][64k], swizzled 8B slots
    __shared__ float fold[8][32];
    const int t  = threadIdx.x;
    const int w  = t >> 6;             // wave 0..7 = col tile
    const int l  = t & 63;
    const int lr = l & 15;
    const int lg = l >> 4;
    const int r0 = blockIdx.x * 32;

    // A staging: thread t covers row (t>>4), slot (t&15) of every chunk
    const int srow  = t >> 4;          // 0..31
    const int sslot = t & 15;
    const int wslot = (sslot ^ (srow & 15)) * 4;   // phys slot, short units
    auto stageHalf = [&](const float* base) {
        const float* ab = base + (size_t)(r0 + srow) * DD + sslot * 4;
        float4 g[8];
#pragma unroll
        for (int j = 0; j < 8; ++j) g[j] = *(const float4*)(ab + j * 64);
#pragma unroll
        for (int j = 0; j < 8; ++j) {
            bf16x4 s;
            s[0]=f2bf(g[j].x); s[1]=f2bf(g[j].y); s[2]=f2bf(g[j].z); s[3]=f2bf(g[j].w);
            *(bf16x4*)&As[srow][j][wslot] = s;
        }
#pragma unroll
        for (int j = 0; j < 8; ++j) g[j] = *(const float4*)(ab + (j + 8) * 64);
#pragma unroll
        for (int j = 0; j < 8; ++j) {
            bf16x4 s;
            s[0]=f2bf(g[j].x); s[1]=f2bf(g[j].y); s[2]=f2bf(g[j].z); s[3]=f2bf(g[j].w);
            *(bf16x4*)&As[srow][j + 8][wslot] = s;
        }
    };

    const int p0 = ((2 * lg)     ^ lr) * 4;
    const int p1 = ((2 * lg + 1) ^ lr) * 4;
    const int p2 = ((2 * lg + 8) ^ lr) * 4;
    const int p3 = ((2 * lg + 9) ^ lr) * 4;

    const short* pB = w1p + (size_t)w * 512 + (size_t)l * 8;
    f32x4 acc0 = (f32x4)0.f, acc1 = (f32x4)0.f;   // rg0 rows 0-15, rg1 rows 16-31
    bf16x8 bA0, bA1, bB0, bB1;

#define LOADB2(h, c, b0, b1_)                                        \
    { const size_t e_ = ((size_t)(h) * 32 + 2 * (c)) * 4096;         \
      b0  = *(const bf16x8*)(pB + e_);                               \
      b1_ = *(const bf16x8*)(pB + e_ + 4096); }

#define FRAGS(c, b0, b1_)                                                   \
    { const short* a0 = &As[lr][c][0];                                      \
      const short* a1 = &As[lr + 16][c][0];                                 \
      bf16x4 g0 = *(const bf16x4*)(a0 + p0);                                \
      bf16x4 g1 = *(const bf16x4*)(a0 + p1);                                \
      bf16x4 g2 = *(const bf16x4*)(a0 + p2);                                \
      bf16x4 g3 = *(const bf16x4*)(a0 + p3);                                \
      bf16x4 h0 = *(const bf16x4*)(a1 + p0);                                \
      bf16x4 h1 = *(const bf16x4*)(a1 + p1);                                \
      bf16x4 h2 = *(const bf16x4*)(a1 + p2);                                \
      bf16x4 h3 = *(const bf16x4*)(a1 + p3);                                \
      bf16x8 aa0 = __builtin_shufflevector(g0, g1, 0,1,2,3,4,5,6,7);        \
      bf16x8 aa1 = __builtin_shufflevector(g2, g3, 0,1,2,3,4,5,6,7);        \
      bf16x8 cc0 = __builtin_shufflevector(h0, h1, 0,1,2,3,4,5,6,7);        \
      bf16x8 cc1 = __builtin_shufflevector(h2, h3, 0,1,2,3,4,5,6,7);        \
      acc0 = __builtin_amdgcn_mfma_f32_16x16x32_bf16(aa0, b0,  acc0, 0,0,0);\
      acc0 = __builtin_amdgcn_mfma_f32_16x16x32_bf16(aa1, b1_, acc0, 0,0,0);\
      acc1 = __builtin_amdgcn_mfma_f32_16x16x32_bf16(cc0, b0,  acc1, 0,0,0);\
      acc1 = __builtin_amdgcn_mfma_f32_16x16x32_bf16(cc1, b1_, acc1, 0,0,0); }

#define COMPUTE_HALF(h)                                              \
    { LOADB2(h, 0, bA0, bA1)                                         \
      _Pragma("unroll 1")                                            \
      for (int c = 0; c < 16; c += 2) {                              \
          LOADB2(h, c + 1, bB0, bB1)                                 \
          FRAGS(c, bA0, bA1)                                         \
          if (c + 2 < 16) { LOADB2(h, c + 2, bA0, bA1) }             \
          FRAGS(c + 1, bB0, bB1)                                     \
      } }

    stageHalf(q);
    __syncthreads();
    COMPUTE_HALF(0)
    __syncthreads();
    stageHalf(x);
    __syncthreads();
    COMPUTE_HALF(1)
#undef LOADB2
#undef FRAGS
#undef COMPUTE_HALF

    // ---- epilogue: bias+relu+W2 per col, 16-lane col reduce, 8-tile fold ----
    const int col = w * 16 + lr;
    const float bb = (col < HH) ? b1[col] : 0.f;
    const float ww = (col < HH) ? W2[col] : 0.f;
#pragma unroll
    for (int r = 0; r < 4; ++r) {
        float v0 = fmaxf(acc0[r] + bb, 0.f) * ww;
        float v1 = fmaxf(acc1[r] + bb, 0.f) * ww;
        v0 += __shfl_xor(v0, 1); v1 += __shfl_xor(v1, 1);
        v0 += __shfl_xor(v0, 2); v1 += __shfl_xor(v1, 2);
        v0 += __shfl_xor(v0, 4); v1 += __shfl_xor(v1, 4);
        v0 += __shfl_xor(v0, 8); v1 += __shfl_xor(v1, 8);
        if (lr == 0) {
            fold[w][lg * 4 + r]      = v0;
            fold[w][16 + lg * 4 + r] = v1;
        }
    }
    __syncthreads();
    if (t < 32) {
        float sv = b2[0];
#pragma unroll
        for (int ws_ = 0; ws_ < 8; ++ws_) sv += fold[ws_][t];
        const int i = r0 + t;
        const int g = bidx[i];
        if (y[i]) {
            int idx = atomicAdd(&cnt1[g], 1);
            if (idx < LCAP) sp[g * LCAP + idx] = sv;
        } else {
            int idx = atomicAdd(&cnt0[g], 1);
            if (idx < LCAP) sn[g * LCAP + idx] = sv;
        }
    }
}

// grid = NB*8 blocks; block (g, sl) handles pos indices p ≡ sl (mod 8).
__global__ __launch_bounds__(256) void pairsum_kernel(
    const float* __restrict__ sp, const float* __restrict__ sn,
    const int* __restrict__ cnt1, const int* __restrict__ cnt0,
    float* __restrict__ partial)
{
    __shared__ float lsn[LCAP];
    __shared__ float lsp[64];
    __shared__ float wsum[4];
    const int g  = blockIdx.x >> 3;
    const int sl = blockIdx.x & 7;
    const int t  = threadIdx.x;
    const int n1 = min(cnt1[g], LCAP);
    const int n0 = min(cnt0[g], LCAP);
    for (int j = t; j < n0; j += 256) lsn[j] = sn[g * LCAP + j];
    const int np = (n1 > sl) ? ((n1 - sl + 7) >> 3) : 0;
    for (int j = t; j < np; j += 256) lsp[j] = sp[g * LCAP + sl + j * 8];
    __syncthreads();
    float acc = 0.f;
    const int total = np * n0;
    for (int u = t; u < total; u += 256) {
        const int ip = u / n0;
        const int j  = u - ip * n0;
        const float d  = lsn[j] - lsp[ip];          // s_neg - s_pos
        const float ad = fabsf(d);
        const float z  = __builtin_exp2f(-ad * 1.44269504f);
        acc += fmaxf(d, 0.f) + __builtin_log2f(1.f + z) * 0.69314718f;
    }
#pragma unroll
    for (int off = 32; off > 0; off >>= 1) acc += __shfl_xor(acc, off, 64);
    const int wid = t >> 6, lane = t & 63;
    if (lane == 0) wsum[wid] = acc;
    __syncthreads();
    if (t == 0) partial[blockIdx.x] = wsum[0] + wsum[1] + wsum[2] + wsum[3];
}

__global__ __launch_bounds__(256) void finalize_kernel(
    const float* __restrict__ partial,
    const int* __restrict__ cnt1, const int* __restrict__ cnt0,
    float* __restrict__ out)
{
    __shared__ float ws_[4], wc_[4];
    const int t = threadIdx.x;
    float sv = partial[t];   // 256 entries
    float cv = 0.f;
    if (t < NB) cv = (float)min(cnt1[t], LCAP) * (float)min(cnt0[t], LCAP);
#pragma unroll
    for (int off = 32; off > 0; off >>= 1) {
        sv += __shfl_xor(sv, off, 64);
        cv += __shfl_xor(cv, off, 64);
    }
    const int wid = t >> 6, lane = t & 63;
    if (lane == 0) { ws_[wid] = sv; wc_[wid] = cv; }
    __syncthreads();
    if (t == 0)
        out[0] = (ws_[0] + ws_[1] + ws_[2] + ws_[3]) /
                 (wc_[0] + wc_[1] + wc_[2] + wc_[3]);
}

extern "C" void kernel_launch(void* const* d_in, const int* in_sizes, int n_in,
                              void* d_out, int out_size, void* d_ws, size_t ws_size,
                              hipStream_t stream)
{
    const int*   b  = (const int*)d_in[0];
    const float* q  = (const float*)d_in[1];
    const float* x  = (const float*)d_in[2];
    const int*   y  = (const int*)d_in[3];
    const float* W1 = (const float*)d_in[4];
    const float* b1 = (const float*)d_in[5];
    const float* W2 = (const float*)d_in[6];
    const float* b2 = (const float*)d_in[7];
    float* out = (float*)d_out;

    char* base = (char*)d_ws;
    short* w1p     = (short*)base;                          // 512 KB packed B
    float* sp      = (float*)(base + 524288);               // 64 KB
    float* sn      = (float*)(base + 524288 + 65536);       // 64 KB
    int*   cnt1    = (int*)(base + 524288 + 131072);        // 128 B
    int*   cnt0    = cnt1 + NB;                             // 128 B
    float* partial = (float*)(base + 524288 + 131072 + 256);// 1 KB

    prep_w1p<<<KT / 32, 256, 0, stream>>>(W1, w1p, cnt1, cnt0);
    encoder_mfma<<<NN / 32, 512, 0, stream>>>(q, x, w1p, b1, W2, b2,
                                              b, y, sp, sn, cnt1, cnt0);
    pairsum_kernel<<<NB * 8, 256, 0, stream>>>(sp, sn, cnt1, cnt0, partial);
    finalize_kernel<<<1, 256, 0, stream>>>(partial, cnt1, cnt0, out);
}